// Round 1
// baseline (1130.542 us; speedup 1.0000x reference)
//
#include <hip/hip_runtime.h>
#include <hip/hip_bf16.h>
#include <math.h>

#define NEG_SLOPE 0.2f

static __device__ __forceinline__ float leaky(float x){ return x > 0.f ? x : NEG_SLOPE * x; }

// ---------------- edge sort by dst (counting sort) ----------------
__global__ void hist_kernel(const int* __restrict__ dst, int E, int* __restrict__ counts){
  int i = blockIdx.x*blockDim.x + threadIdx.x;
  if(i < E) atomicAdd(&counts[dst[i]], 1);
}

__global__ void scan_kernel(const int* __restrict__ counts, int N,
                            int* __restrict__ offsets, int* __restrict__ cursor){
  __shared__ int sdata[1024];
  __shared__ int s_run;
  if(threadIdx.x==0) s_run = 0;
  __syncthreads();
  for(int base=0; base<N; base+=1024){
    int i = base + (int)threadIdx.x;
    int v = (i<N) ? counts[i] : 0;
    sdata[threadIdx.x] = v;
    __syncthreads();
    for(int off=1; off<1024; off<<=1){
      int t = (threadIdx.x >= off) ? sdata[threadIdx.x-off] : 0;
      __syncthreads();
      sdata[threadIdx.x] += t;
      __syncthreads();
    }
    int incl = sdata[threadIdx.x];
    int excl = incl - v;
    if(i<N){ offsets[i] = s_run + excl; cursor[i] = s_run + excl; }
    __syncthreads();
    if(threadIdx.x==1023) s_run += incl;
    __syncthreads();
  }
  if(threadIdx.x==0) offsets[N] = s_run;
}

__global__ void scatter_kernel(const int* __restrict__ src, const int* __restrict__ dst, int E,
                               int* __restrict__ cursor, int* __restrict__ ssrc){
  int i = blockIdx.x*blockDim.x + threadIdx.x;
  if(i < E){
    int p = atomicAdd(&cursor[dst[i]], 1);
    ssrc[p] = src[i];
  }
}

// ---------------- fp32 tiled GEMM: C[M,N] = A[M,K] @ B[K,N] ----------------
// tile 64x64, 256 threads, each thread 4x4, K-step 16
__global__ void gemm64(const float* __restrict__ A, const float* __restrict__ B,
                       float* __restrict__ Cm, int M, int N, int K){
  __shared__ float As[16][64];   // [k][m] (transposed stage)
  __shared__ float Bs[16][64];   // [k][n]
  const int tx = threadIdx.x & 15;
  const int ty = threadIdx.x >> 4;
  const int m0 = blockIdx.y * 64;
  const int n0 = blockIdx.x * 64;
  const int arow = threadIdx.x >> 2;      // 0..63
  const int akq  = threadIdx.x & 3;       // 0..3 (k quad)
  const int bk   = threadIdx.x >> 4;      // 0..15
  const int bn   = (threadIdx.x & 15) * 4;
  float acc[4][4] = {};
  for(int k0=0; k0<K; k0+=16){
    float4 av = make_float4(0.f,0.f,0.f,0.f);
    int gm = m0 + arow;
    if(gm < M) av = *(const float4*)&A[(size_t)gm*K + k0 + akq*4];
    As[akq*4+0][arow]=av.x; As[akq*4+1][arow]=av.y;
    As[akq*4+2][arow]=av.z; As[akq*4+3][arow]=av.w;
    float4 bv = make_float4(0.f,0.f,0.f,0.f);
    int gn = n0 + bn;
    const float* brow = &B[(size_t)(k0+bk)*N];
    if(gn + 3 < N) bv = *(const float4*)&brow[gn];
    else {
      if(gn   < N) bv.x = brow[gn];
      if(gn+1 < N) bv.y = brow[gn+1];
      if(gn+2 < N) bv.z = brow[gn+2];
    }
    *(float4*)&Bs[bk][bn] = bv;
    __syncthreads();
    #pragma unroll
    for(int k=0;k<16;k++){
      float4 a4 = *(const float4*)&As[k][ty*4];
      float4 b4 = *(const float4*)&Bs[k][tx*4];
      float aa[4] = {a4.x,a4.y,a4.z,a4.w};
      float bb[4] = {b4.x,b4.y,b4.z,b4.w};
      #pragma unroll
      for(int i=0;i<4;i++)
        #pragma unroll
        for(int j=0;j<4;j++)
          acc[i][j] = fmaf(aa[i], bb[j], acc[i][j]);
    }
    __syncthreads();
  }
  #pragma unroll
  for(int i=0;i<4;i++){
    int gm = m0 + ty*4 + i;
    if(gm >= M) continue;
    int gn = n0 + tx*4;
    if(gn + 3 < N){
      float4 o = make_float4(acc[i][0],acc[i][1],acc[i][2],acc[i][3]);
      *(float4*)&Cm[(size_t)gm*N + gn] = o;
    } else {
      #pragma unroll
      for(int j=0;j<4;j++) if(gn+j < N) Cm[(size_t)gm*N + gn + j] = acc[i][j];
    }
  }
}

// ---------------- el/er projections: [N,H] dot over D ----------------
// block = 256 = 4 waves; wave h handles head h, lanes over D
__global__ void attn_proj(const float* __restrict__ feat, const float* __restrict__ a_l,
                          const float* __restrict__ a_r, float* __restrict__ el,
                          float* __restrict__ er, int D){
  int n = blockIdx.x;
  int h = threadIdx.x >> 6;
  int lane = threadIdx.x & 63;
  float vl = 0.f, vr = 0.f;
  for(int d=lane; d<D; d+=64){
    float f = feat[(size_t)n*4*D + h*D + d];
    vl = fmaf(f, a_l[h*D+d], vl);
    vr = fmaf(f, a_r[h*D+d], vr);
  }
  #pragma unroll
  for(int off=32; off; off>>=1){ vl += __shfl_down(vl,off); vr += __shfl_down(vr,off); }
  if(lane==0){ el[n*4+h] = vl; er[n*4+h] = vr; }
}

// ---------------- softmax + aggregate, layers 0/1 (H*D=256), ELU ----------------
// one block (256 thr) per dst node; edges pre-sorted by dst; no atomics
__global__ void agg_kernel(const float* __restrict__ feat, const float* __restrict__ el,
                           const float* __restrict__ er, const int* __restrict__ offsets,
                           const int* __restrict__ ssrc, const float* __restrict__ bias,
                           float* __restrict__ outp){
  int n = blockIdx.x;
  int tid = threadIdx.x;          // owns (h,d): h=tid>>6, d=tid&63
  int h = tid >> 6;
  int e0 = offsets[n], e1 = offsets[n+1];
  float ern = er[n*4+h];
  float acc = 0.f, denom = 0.f;
  for(int e=e0; e<e1; e++){
    int s = ssrc[e];
    float ee = __expf(leaky(el[s*4+h] + ern));
    denom += ee;
    acc = fmaf(ee, feat[(size_t)s*256 + tid], acc);
  }
  float o = acc / fmaxf(denom, 1e-9f) + bias[tid];
  o = o > 0.f ? o : (__expf(o) - 1.f);   // ELU
  outp[(size_t)n*256 + tid] = o;
}

// ---------------- layer 2: aggregate (H*C=160) + head-mean logits ----------------
__global__ void agg2_kernel(const float* __restrict__ feat, const float* __restrict__ el,
                            const float* __restrict__ er, const int* __restrict__ offsets,
                            const int* __restrict__ ssrc, const float* __restrict__ bias,
                            float* __restrict__ logits){
  int n = blockIdx.x;
  int tid = threadIdx.x;          // 192 threads, tid<160 active: h=tid/40, c=tid%40
  __shared__ float s_out[160];
  int e0 = offsets[n], e1 = offsets[n+1];
  if(tid < 160){
    int h = tid / 40;
    float ern = er[n*4+h];
    float acc = 0.f, denom = 0.f;
    for(int e=e0; e<e1; e++){
      int s = ssrc[e];
      float ee = __expf(leaky(el[s*4+h] + ern));
      denom += ee;
      acc = fmaf(ee, feat[(size_t)s*160 + tid], acc);
    }
    s_out[tid] = acc / fmaxf(denom, 1e-9f) + bias[tid];
  }
  __syncthreads();
  if(tid < 40){
    logits[(size_t)n*40 + tid] =
        0.25f * (s_out[tid] + s_out[40+tid] + s_out[80+tid] + s_out[120+tid]);
  }
}

extern "C" void kernel_launch(void* const* d_in, const int* in_sizes, int n_in,
                              void* d_out, int out_size, void* d_ws, size_t ws_size,
                              hipStream_t stream){
  const float* x   = (const float*)d_in[0];
  const int*   eix = (const int*)  d_in[1];
  const float* W0  = (const float*)d_in[2];
  const float* al0 = (const float*)d_in[3];
  const float* ar0 = (const float*)d_in[4];
  const float* b0  = (const float*)d_in[5];
  const float* W1  = (const float*)d_in[6];
  const float* al1 = (const float*)d_in[7];
  const float* ar1 = (const float*)d_in[8];
  const float* b1  = (const float*)d_in[9];
  const float* W2  = (const float*)d_in[10];
  const float* al2 = (const float*)d_in[11];
  const float* ar2 = (const float*)d_in[12];
  const float* b2  = (const float*)d_in[13];
  float* logits = (float*)d_out;

  const int N = in_sizes[0] / 256;   // 50000
  const int E = in_sizes[1] / 2;     // 800000
  const int* src = eix;
  const int* dst = eix + E;

  char* ws = (char*)d_ws;
  auto alloc = [&](size_t bytes)->char*{
    char* p = ws; ws += (bytes + 255) & ~(size_t)255; return p;
  };
  int*   counts  = (int*)  alloc((size_t)N*4);
  int*   offsets = (int*)  alloc((size_t)(N+1)*4);
  int*   cursor  = (int*)  alloc((size_t)N*4);
  int*   ssrc    = (int*)  alloc((size_t)E*4);
  float* bufF    = (float*)alloc((size_t)N*256*4);
  float* bufH    = (float*)alloc((size_t)N*256*4);
  float* el_buf  = (float*)alloc((size_t)N*4*4);
  float* er_buf  = (float*)alloc((size_t)N*4*4);

  // sort edges by dst (graph fixed across layers — one sort per call)
  hipMemsetAsync(counts, 0, (size_t)N*4, stream);
  hist_kernel   <<<(E+255)/256, 256, 0, stream>>>(dst, E, counts);
  scan_kernel   <<<1, 1024, 0, stream>>>(counts, N, offsets, cursor);
  scatter_kernel<<<(E+255)/256, 256, 0, stream>>>(src, dst, E, cursor, ssrc);

  dim3 g01(256/64, (N+63)/64);
  // layer 0
  gemm64   <<<g01, 256, 0, stream>>>(x, W0, bufF, N, 256, 256);
  attn_proj<<<N, 256, 0, stream>>>(bufF, al0, ar0, el_buf, er_buf, 64);
  agg_kernel<<<N, 256, 0, stream>>>(bufF, el_buf, er_buf, offsets, ssrc, b0, bufH);
  // layer 1
  gemm64   <<<g01, 256, 0, stream>>>(bufH, W1, bufF, N, 256, 256);
  attn_proj<<<N, 256, 0, stream>>>(bufF, al1, ar1, el_buf, er_buf, 64);
  agg_kernel<<<N, 256, 0, stream>>>(bufF, el_buf, er_buf, offsets, ssrc, b1, bufH);
  // layer 2
  dim3 g2((160+63)/64, (N+63)/64);
  gemm64   <<<g2, 256, 0, stream>>>(bufH, W2, bufF, N, 160, 256);
  attn_proj<<<N, 256, 0, stream>>>(bufF, al2, ar2, el_buf, er_buf, 40);
  agg2_kernel<<<N, 192, 0, stream>>>(bufF, el_buf, er_buf, offsets, ssrc, b2, logits);
}

// Round 2
// 958.597 us; speedup vs baseline: 1.1794x; 1.1794x over previous
//
#include <hip/hip_runtime.h>
#include <hip/hip_bf16.h>
#include <math.h>

#define NEG_SLOPE 0.2f

static __device__ __forceinline__ float leaky(float x){ return x > 0.f ? x : NEG_SLOPE * x; }
static __device__ __forceinline__ float elu(float x){ return x > 0.f ? x : (__expf(x) - 1.f); }

// ---------------- edge sort by dst (counting sort) ----------------
__global__ void hist_kernel(const int* __restrict__ dst, int E, int* __restrict__ counts){
  int i = blockIdx.x*blockDim.x + threadIdx.x;
  if(i < E) atomicAdd(&counts[dst[i]], 1);
}

__global__ void scan_kernel(const int* __restrict__ counts, int N,
                            int* __restrict__ offsets, int* __restrict__ cursor){
  __shared__ int sdata[1024];
  __shared__ int s_run;
  if(threadIdx.x==0) s_run = 0;
  __syncthreads();
  for(int base=0; base<N; base+=1024){
    int i = base + (int)threadIdx.x;
    int v = (i<N) ? counts[i] : 0;
    sdata[threadIdx.x] = v;
    __syncthreads();
    for(int off=1; off<1024; off<<=1){
      int t = (threadIdx.x >= off) ? sdata[threadIdx.x-off] : 0;
      __syncthreads();
      sdata[threadIdx.x] += t;
      __syncthreads();
    }
    int incl = sdata[threadIdx.x];
    int excl = incl - v;
    if(i<N){ offsets[i] = s_run + excl; cursor[i] = s_run + excl; }
    __syncthreads();
    if(threadIdx.x==1023) s_run += incl;
    __syncthreads();
  }
  if(threadIdx.x==0) offsets[N] = s_run;
}

__global__ void scatter_kernel(const int* __restrict__ src, const int* __restrict__ dst, int E,
                               int* __restrict__ cursor, int* __restrict__ ssrc){
  int i = blockIdx.x*blockDim.x + threadIdx.x;
  if(i < E){
    int p = atomicAdd(&cursor[dst[i]], 1);
    ssrc[p] = src[i];
  }
}

// ---------------- fp32 tiled GEMM: C[M,N] = A[M,K] @ B[K,N] ----------------
// tile 128x64, 256 threads, each thread 8x4, K-step 16
__global__ __launch_bounds__(256) void gemm128(const float* __restrict__ A, const float* __restrict__ B,
                       float* __restrict__ Cm, int M, int N, int K){
  __shared__ float As[16][128];   // [k][m]
  __shared__ float Bs[16][64];    // [k][n]
  const int tid = threadIdx.x;
  const int tx = tid & 15;
  const int ty = tid >> 4;
  const int m0 = blockIdx.y * 128;
  const int n0 = blockIdx.x * 64;
  const int arow = tid >> 1;           // 0..127
  const int aq   = (tid & 1) * 8;      // k-offset 0 or 8
  const int bk   = tid >> 4;           // 0..15
  const int bn   = (tid & 15) * 4;
  float acc[8][4] = {};
  for(int k0=0; k0<K; k0+=16){
    float4 a0 = make_float4(0.f,0.f,0.f,0.f), a1 = a0;
    int gm = m0 + arow;
    if(gm < M){
      a0 = *(const float4*)&A[(size_t)gm*K + k0 + aq];
      a1 = *(const float4*)&A[(size_t)gm*K + k0 + aq + 4];
    }
    As[aq+0][arow]=a0.x; As[aq+1][arow]=a0.y; As[aq+2][arow]=a0.z; As[aq+3][arow]=a0.w;
    As[aq+4][arow]=a1.x; As[aq+5][arow]=a1.y; As[aq+6][arow]=a1.z; As[aq+7][arow]=a1.w;
    float4 bv = make_float4(0.f,0.f,0.f,0.f);
    int gn = n0 + bn;
    const float* brow = &B[(size_t)(k0+bk)*N];
    if(gn + 3 < N) bv = *(const float4*)&brow[gn];
    else {
      if(gn   < N) bv.x = brow[gn];
      if(gn+1 < N) bv.y = brow[gn+1];
      if(gn+2 < N) bv.z = brow[gn+2];
    }
    *(float4*)&Bs[bk][bn] = bv;
    __syncthreads();
    #pragma unroll
    for(int k=0;k<16;k++){
      float4 b4  = *(const float4*)&Bs[k][tx*4];
      float4 a04 = *(const float4*)&As[k][ty*8];
      float4 a14 = *(const float4*)&As[k][ty*8+4];
      float aa[8] = {a04.x,a04.y,a04.z,a04.w,a14.x,a14.y,a14.z,a14.w};
      float bb[4] = {b4.x,b4.y,b4.z,b4.w};
      #pragma unroll
      for(int i=0;i<8;i++)
        #pragma unroll
        for(int j=0;j<4;j++)
          acc[i][j] = fmaf(aa[i], bb[j], acc[i][j]);
    }
    __syncthreads();
  }
  #pragma unroll
  for(int i=0;i<8;i++){
    int gm = m0 + ty*8 + i;
    if(gm >= M) continue;
    int gn = n0 + tx*4;
    if(gn + 3 < N){
      float4 o = make_float4(acc[i][0],acc[i][1],acc[i][2],acc[i][3]);
      *(float4*)&Cm[(size_t)gm*N + gn] = o;
    } else {
      #pragma unroll
      for(int j=0;j<4;j++) if(gn+j < N) Cm[(size_t)gm*N + gn + j] = acc[i][j];
    }
  }
}

// ---------------- el/er projections: [N,H] dot over D ----------------
__global__ void attn_proj(const float* __restrict__ feat, const float* __restrict__ a_l,
                          const float* __restrict__ a_r, float* __restrict__ el,
                          float* __restrict__ er, int D){
  int n = blockIdx.x;
  int h = threadIdx.x >> 6;
  int lane = threadIdx.x & 63;
  float vl = 0.f, vr = 0.f;
  for(int d=lane; d<D; d+=64){
    float f = feat[(size_t)n*4*D + h*D + d];
    vl = fmaf(f, a_l[h*D+d], vl);
    vr = fmaf(f, a_r[h*D+d], vr);
  }
  #pragma unroll
  for(int off=32; off; off>>=1){ vl += __shfl_down(vl,off); vr += __shfl_down(vr,off); }
  if(lane==0){ el[n*4+h] = vl; er[n*4+h] = vr; }
}

// ---------------- softmax + aggregate, layers 0/1 (H*D=256), ELU ----------------
// one WAVE per dst node; lane holds float4 of the 256-wide feature row
__global__ __launch_bounds__(256) void agg_kernel(const float4* __restrict__ feat4,
                           const float* __restrict__ el, const float* __restrict__ er,
                           const int* __restrict__ offsets, const int* __restrict__ ssrc,
                           const float* __restrict__ bias, float* __restrict__ outp, int N){
  int wv = threadIdx.x >> 6;
  int lane = threadIdx.x & 63;
  int n = blockIdx.x*4 + wv;
  if(n >= N) return;
  int h = lane >> 4;                 // floats lane*4..+3 all in head lane>>4 (64 floats/head)
  float ern = er[n*4+h];
  int e0 = offsets[n], e1 = offsets[n+1];
  float4 acc = make_float4(0.f,0.f,0.f,0.f);
  float denom = 0.f;
  for(int e=e0; e<e1; e++){
    int s = ssrc[e];
    float w = __expf(leaky(el[s*4+h] + ern));
    float4 f = feat4[(size_t)s*64 + lane];
    acc.x = fmaf(w, f.x, acc.x);
    acc.y = fmaf(w, f.y, acc.y);
    acc.z = fmaf(w, f.z, acc.z);
    acc.w = fmaf(w, f.w, acc.w);
    denom += w;
  }
  float inv = 1.f / fmaxf(denom, 1e-9f);
  float4 b4 = *(const float4*)&bias[lane*4];
  float4 o;
  o.x = elu(acc.x*inv + b4.x);
  o.y = elu(acc.y*inv + b4.y);
  o.z = elu(acc.z*inv + b4.z);
  o.w = elu(acc.w*inv + b4.w);
  *(float4*)&outp[(size_t)n*256 + lane*4] = o;
}

// ---------------- layer 2: aggregate (H*C=160) + head-mean logits ----------------
// one wave per node, lanes 0..39 hold float4 of the 160-wide row
__global__ __launch_bounds__(256) void agg2_kernel(const float4* __restrict__ feat4,
                            const float* __restrict__ el, const float* __restrict__ er,
                            const int* __restrict__ offsets, const int* __restrict__ ssrc,
                            const float* __restrict__ bias, float* __restrict__ logits, int N){
  __shared__ float s_out[4][160];
  int wv = threadIdx.x >> 6;
  int lane = threadIdx.x & 63;
  int n = blockIdx.x*4 + wv;
  bool valid = (n < N);
  if(valid && lane < 40){
    int h = lane / 10;               // floats lane*4..+3, head = (lane*4)/40
    float ern = er[n*4+h];
    int e0 = offsets[n], e1 = offsets[n+1];
    float4 acc = make_float4(0.f,0.f,0.f,0.f);
    float denom = 0.f;
    for(int e=e0; e<e1; e++){
      int s = ssrc[e];
      float w = __expf(leaky(el[s*4+h] + ern));
      float4 f = feat4[(size_t)s*40 + lane];
      acc.x = fmaf(w, f.x, acc.x);
      acc.y = fmaf(w, f.y, acc.y);
      acc.z = fmaf(w, f.z, acc.z);
      acc.w = fmaf(w, f.w, acc.w);
      denom += w;
    }
    float inv = 1.f / fmaxf(denom, 1e-9f);
    float4 b4 = *(const float4*)&bias[lane*4];
    s_out[wv][lane*4+0] = acc.x*inv + b4.x;
    s_out[wv][lane*4+1] = acc.y*inv + b4.y;
    s_out[wv][lane*4+2] = acc.z*inv + b4.z;
    s_out[wv][lane*4+3] = acc.w*inv + b4.w;
  }
  __syncthreads();
  if(valid && lane < 40){
    logits[(size_t)n*40 + lane] =
        0.25f * (s_out[wv][lane] + s_out[wv][40+lane] + s_out[wv][80+lane] + s_out[wv][120+lane]);
  }
}

extern "C" void kernel_launch(void* const* d_in, const int* in_sizes, int n_in,
                              void* d_out, int out_size, void* d_ws, size_t ws_size,
                              hipStream_t stream){
  const float* x   = (const float*)d_in[0];
  const int*   eix = (const int*)  d_in[1];
  const float* W0  = (const float*)d_in[2];
  const float* al0 = (const float*)d_in[3];
  const float* ar0 = (const float*)d_in[4];
  const float* b0  = (const float*)d_in[5];
  const float* W1  = (const float*)d_in[6];
  const float* al1 = (const float*)d_in[7];
  const float* ar1 = (const float*)d_in[8];
  const float* b1  = (const float*)d_in[9];
  const float* W2  = (const float*)d_in[10];
  const float* al2 = (const float*)d_in[11];
  const float* ar2 = (const float*)d_in[12];
  const float* b2  = (const float*)d_in[13];
  float* logits = (float*)d_out;

  const int N = in_sizes[0] / 256;   // 50000
  const int E = in_sizes[1] / 2;     // 800000
  const int* src = eix;
  const int* dst = eix + E;

  char* ws = (char*)d_ws;
  auto alloc = [&](size_t bytes)->char*{
    char* p = ws; ws += (bytes + 255) & ~(size_t)255; return p;
  };
  int*   counts  = (int*)  alloc((size_t)N*4);
  int*   offsets = (int*)  alloc((size_t)(N+1)*4);
  int*   cursor  = (int*)  alloc((size_t)N*4);
  int*   ssrc    = (int*)  alloc((size_t)E*4);
  float* bufF    = (float*)alloc((size_t)N*256*4);
  float* bufH    = (float*)alloc((size_t)N*256*4);
  float* el_buf  = (float*)alloc((size_t)N*4*4);
  float* er_buf  = (float*)alloc((size_t)N*4*4);

  // sort edges by dst (graph fixed across layers — one sort per call)
  hipMemsetAsync(counts, 0, (size_t)N*4, stream);
  hist_kernel   <<<(E+255)/256, 256, 0, stream>>>(dst, E, counts);
  scan_kernel   <<<1, 1024, 0, stream>>>(counts, N, offsets, cursor);
  scatter_kernel<<<(E+255)/256, 256, 0, stream>>>(src, dst, E, cursor, ssrc);

  dim3 g01(256/64, (N+127)/128);
  int aggGrid = (N+3)/4;
  // layer 0
  gemm128  <<<g01, 256, 0, stream>>>(x, W0, bufF, N, 256, 256);
  attn_proj<<<N, 256, 0, stream>>>(bufF, al0, ar0, el_buf, er_buf, 64);
  agg_kernel<<<aggGrid, 256, 0, stream>>>((const float4*)bufF, el_buf, er_buf, offsets, ssrc, b0, bufH, N);
  // layer 1
  gemm128  <<<g01, 256, 0, stream>>>(bufH, W1, bufF, N, 256, 256);
  attn_proj<<<N, 256, 0, stream>>>(bufF, al1, ar1, el_buf, er_buf, 64);
  agg_kernel<<<aggGrid, 256, 0, stream>>>((const float4*)bufF, el_buf, er_buf, offsets, ssrc, b1, bufH, N);
  // layer 2
  dim3 g2((160+63)/64, (N+127)/128);
  gemm128  <<<g2, 256, 0, stream>>>(bufH, W2, bufF, N, 160, 256);
  attn_proj<<<N, 256, 0, stream>>>(bufF, al2, ar2, el_buf, er_buf, 40);
  agg2_kernel<<<aggGrid, 256, 0, stream>>>((const float4*)bufF, el_buf, er_buf, offsets, ssrc, b2, logits, N);
}

// Round 3
// 945.007 us; speedup vs baseline: 1.1963x; 1.0144x over previous
//
#include <hip/hip_runtime.h>
#include <hip/hip_bf16.h>
#include <math.h>

#define NEG_SLOPE 0.2f

static __device__ __forceinline__ float leaky(float x){ return x > 0.f ? x : NEG_SLOPE * x; }
static __device__ __forceinline__ float elu(float x){ return x > 0.f ? x : (__expf(x) - 1.f); }

// ---------------- edge sort by dst (counting sort) ----------------
__global__ void hist_kernel(const int* __restrict__ dst, int E, int* __restrict__ counts){
  int i = blockIdx.x*blockDim.x + threadIdx.x;
  if(i < E) atomicAdd(&counts[dst[i]], 1);
}

__global__ void scan_kernel(const int* __restrict__ counts, int N,
                            int* __restrict__ offsets, int* __restrict__ cursor){
  __shared__ int sdata[1024];
  __shared__ int s_run;
  if(threadIdx.x==0) s_run = 0;
  __syncthreads();
  for(int base=0; base<N; base+=1024){
    int i = base + (int)threadIdx.x;
    int v = (i<N) ? counts[i] : 0;
    sdata[threadIdx.x] = v;
    __syncthreads();
    for(int off=1; off<1024; off<<=1){
      int t = (threadIdx.x >= off) ? sdata[threadIdx.x-off] : 0;
      __syncthreads();
      sdata[threadIdx.x] += t;
      __syncthreads();
    }
    int incl = sdata[threadIdx.x];
    int excl = incl - v;
    if(i<N){ offsets[i] = s_run + excl; cursor[i] = s_run + excl; }
    __syncthreads();
    if(threadIdx.x==1023) s_run += incl;
    __syncthreads();
  }
  if(threadIdx.x==0) offsets[N] = s_run;
}

__global__ void scatter_kernel(const int* __restrict__ src, const int* __restrict__ dst, int E,
                               int* __restrict__ cursor, int* __restrict__ ssrc,
                               int* __restrict__ sdst){
  int i = blockIdx.x*blockDim.x + threadIdx.x;
  if(i < E){
    int d = dst[i];
    int p = atomicAdd(&cursor[d], 1);
    ssrc[p] = src[i];
    sdst[p] = d;
  }
}

// ---------------- per-edge softmax numerators (all 4 heads) ----------------
__global__ __launch_bounds__(256) void edge_w_kernel(const int* __restrict__ ssrc,
                              const int* __restrict__ sdst, int E,
                              const float4* __restrict__ el4, const float4* __restrict__ er4,
                              float4* __restrict__ ew){
  int e = blockIdx.x*blockDim.x + threadIdx.x;
  if(e >= E) return;
  int s = ssrc[e], d = sdst[e];
  float4 l = el4[s], r = er4[d];
  float4 w;
  w.x = __expf(leaky(l.x + r.x));
  w.y = __expf(leaky(l.y + r.y));
  w.z = __expf(leaky(l.z + r.z));
  w.w = __expf(leaky(l.w + r.w));
  ew[e] = w;
}

// ---------------- fp32 tiled GEMM: C[M,N] = A[M,K] @ B[K,N] ----------------
// tile 128x64, 256 threads, each thread 8x4, K-step 16
__global__ __launch_bounds__(256) void gemm128(const float* __restrict__ A, const float* __restrict__ B,
                       float* __restrict__ Cm, int M, int N, int K){
  __shared__ float As[16][128];   // [k][m]
  __shared__ float Bs[16][64];    // [k][n]
  const int tid = threadIdx.x;
  const int tx = tid & 15;
  const int ty = tid >> 4;
  const int m0 = blockIdx.y * 128;
  const int n0 = blockIdx.x * 64;
  const int arow = tid >> 1;           // 0..127
  const int aq   = (tid & 1) * 8;      // k-offset 0 or 8
  const int bk   = tid >> 4;           // 0..15
  const int bn   = (tid & 15) * 4;
  float acc[8][4] = {};
  for(int k0=0; k0<K; k0+=16){
    float4 a0 = make_float4(0.f,0.f,0.f,0.f), a1 = a0;
    int gm = m0 + arow;
    if(gm < M){
      a0 = *(const float4*)&A[(size_t)gm*K + k0 + aq];
      a1 = *(const float4*)&A[(size_t)gm*K + k0 + aq + 4];
    }
    As[aq+0][arow]=a0.x; As[aq+1][arow]=a0.y; As[aq+2][arow]=a0.z; As[aq+3][arow]=a0.w;
    As[aq+4][arow]=a1.x; As[aq+5][arow]=a1.y; As[aq+6][arow]=a1.z; As[aq+7][arow]=a1.w;
    float4 bv = make_float4(0.f,0.f,0.f,0.f);
    int gn = n0 + bn;
    const float* brow = &B[(size_t)(k0+bk)*N];
    if(gn + 3 < N) bv = *(const float4*)&brow[gn];
    else {
      if(gn   < N) bv.x = brow[gn];
      if(gn+1 < N) bv.y = brow[gn+1];
      if(gn+2 < N) bv.z = brow[gn+2];
    }
    *(float4*)&Bs[bk][bn] = bv;
    __syncthreads();
    #pragma unroll
    for(int k=0;k<16;k++){
      float4 b4  = *(const float4*)&Bs[k][tx*4];
      float4 a04 = *(const float4*)&As[k][ty*8];
      float4 a14 = *(const float4*)&As[k][ty*8+4];
      float aa[8] = {a04.x,a04.y,a04.z,a04.w,a14.x,a14.y,a14.z,a14.w};
      float bb[4] = {b4.x,b4.y,b4.z,b4.w};
      #pragma unroll
      for(int i=0;i<8;i++)
        #pragma unroll
        for(int j=0;j<4;j++)
          acc[i][j] = fmaf(aa[i], bb[j], acc[i][j]);
    }
    __syncthreads();
  }
  #pragma unroll
  for(int i=0;i<8;i++){
    int gm = m0 + ty*8 + i;
    if(gm >= M) continue;
    int gn = n0 + tx*4;
    if(gn + 3 < N){
      float4 o = make_float4(acc[i][0],acc[i][1],acc[i][2],acc[i][3]);
      *(float4*)&Cm[(size_t)gm*N + gn] = o;
    } else {
      #pragma unroll
      for(int j=0;j<4;j++) if(gn+j < N) Cm[(size_t)gm*N + gn + j] = acc[i][j];
    }
  }
}

// ---------------- el/er projections: [N,H] dot over D ----------------
__global__ void attn_proj(const float* __restrict__ feat, const float* __restrict__ a_l,
                          const float* __restrict__ a_r, float* __restrict__ el,
                          float* __restrict__ er, int D){
  int n = blockIdx.x;
  int h = threadIdx.x >> 6;
  int lane = threadIdx.x & 63;
  float vl = 0.f, vr = 0.f;
  for(int d=lane; d<D; d+=64){
    float f = feat[(size_t)n*4*D + h*D + d];
    vl = fmaf(f, a_l[h*D+d], vl);
    vr = fmaf(f, a_r[h*D+d], vr);
  }
  #pragma unroll
  for(int off=32; off; off>>=1){ vl += __shfl_down(vl,off); vr += __shfl_down(vr,off); }
  if(lane==0){ el[n*4+h] = vl; er[n*4+h] = vr; }
}

// ---------------- softmax + aggregate, layers 0/1 (H*D=256), ELU ----------------
// one WAVE per dst node; lane holds float4 of the 256-wide feature row.
// edge weights precomputed (ew); edge loop unrolled x4 w/ independent accs for MLP
__global__ __launch_bounds__(256) void agg_kernel(const float4* __restrict__ feat4,
                           const float* __restrict__ ew,
                           const int* __restrict__ offsets, const int* __restrict__ ssrc,
                           const float* __restrict__ bias, float* __restrict__ outp, int N){
  int wv = threadIdx.x >> 6;
  int lane = threadIdx.x & 63;
  int n = blockIdx.x*4 + wv;
  if(n >= N) return;
  int h = lane >> 4;                 // floats lane*4..+3 all in head lane>>4 (64 floats/head)
  int e0 = offsets[n], e1 = offsets[n+1];
  float4 acc0 = make_float4(0.f,0.f,0.f,0.f), acc1 = acc0, acc2 = acc0, acc3 = acc0;
  float den0 = 0.f, den1 = 0.f, den2 = 0.f, den3 = 0.f;
  int e = e0;
  for(; e+3 < e1; e += 4){
    int s0 = ssrc[e], s1 = ssrc[e+1], s2 = ssrc[e+2], s3 = ssrc[e+3];
    float w0 = ew[(size_t)e*4 + h];
    float w1 = ew[(size_t)(e+1)*4 + h];
    float w2 = ew[(size_t)(e+2)*4 + h];
    float w3 = ew[(size_t)(e+3)*4 + h];
    float4 f0 = feat4[(size_t)s0*64 + lane];
    float4 f1 = feat4[(size_t)s1*64 + lane];
    float4 f2 = feat4[(size_t)s2*64 + lane];
    float4 f3 = feat4[(size_t)s3*64 + lane];
    acc0.x = fmaf(w0,f0.x,acc0.x); acc0.y = fmaf(w0,f0.y,acc0.y);
    acc0.z = fmaf(w0,f0.z,acc0.z); acc0.w = fmaf(w0,f0.w,acc0.w); den0 += w0;
    acc1.x = fmaf(w1,f1.x,acc1.x); acc1.y = fmaf(w1,f1.y,acc1.y);
    acc1.z = fmaf(w1,f1.z,acc1.z); acc1.w = fmaf(w1,f1.w,acc1.w); den1 += w1;
    acc2.x = fmaf(w2,f2.x,acc2.x); acc2.y = fmaf(w2,f2.y,acc2.y);
    acc2.z = fmaf(w2,f2.z,acc2.z); acc2.w = fmaf(w2,f2.w,acc2.w); den2 += w2;
    acc3.x = fmaf(w3,f3.x,acc3.x); acc3.y = fmaf(w3,f3.y,acc3.y);
    acc3.z = fmaf(w3,f3.z,acc3.z); acc3.w = fmaf(w3,f3.w,acc3.w); den3 += w3;
  }
  for(; e < e1; e++){
    int s = ssrc[e];
    float w = ew[(size_t)e*4 + h];
    float4 f = feat4[(size_t)s*64 + lane];
    acc0.x = fmaf(w,f.x,acc0.x); acc0.y = fmaf(w,f.y,acc0.y);
    acc0.z = fmaf(w,f.z,acc0.z); acc0.w = fmaf(w,f.w,acc0.w); den0 += w;
  }
  float denom = (den0+den1) + (den2+den3);
  float4 acc;
  acc.x = (acc0.x+acc1.x) + (acc2.x+acc3.x);
  acc.y = (acc0.y+acc1.y) + (acc2.y+acc3.y);
  acc.z = (acc0.z+acc1.z) + (acc2.z+acc3.z);
  acc.w = (acc0.w+acc1.w) + (acc2.w+acc3.w);
  float inv = 1.f / fmaxf(denom, 1e-9f);
  float4 b4 = *(const float4*)&bias[lane*4];
  float4 o;
  o.x = elu(acc.x*inv + b4.x);
  o.y = elu(acc.y*inv + b4.y);
  o.z = elu(acc.z*inv + b4.z);
  o.w = elu(acc.w*inv + b4.w);
  *(float4*)&outp[(size_t)n*256 + lane*4] = o;
}

// ---------------- layer 2: aggregate (H*C=160) + head-mean logits ----------------
// one wave per node, lanes 0..39 hold float4 of the 160-wide row
__global__ __launch_bounds__(256) void agg2_kernel(const float4* __restrict__ feat4,
                            const float* __restrict__ ew,
                            const int* __restrict__ offsets, const int* __restrict__ ssrc,
                            const float* __restrict__ bias, float* __restrict__ logits, int N){
  __shared__ float s_out[4][160];
  int wv = threadIdx.x >> 6;
  int lane = threadIdx.x & 63;
  int n = blockIdx.x*4 + wv;
  bool valid = (n < N);
  if(valid && lane < 40){
    int h = lane / 10;               // floats lane*4..+3, head = (lane*4)/40
    int e0 = offsets[n], e1 = offsets[n+1];
    float4 acc0 = make_float4(0.f,0.f,0.f,0.f), acc1 = acc0, acc2 = acc0, acc3 = acc0;
    float den0 = 0.f, den1 = 0.f, den2 = 0.f, den3 = 0.f;
    int e = e0;
    for(; e+3 < e1; e += 4){
      int s0 = ssrc[e], s1 = ssrc[e+1], s2 = ssrc[e+2], s3 = ssrc[e+3];
      float w0 = ew[(size_t)e*4 + h];
      float w1 = ew[(size_t)(e+1)*4 + h];
      float w2 = ew[(size_t)(e+2)*4 + h];
      float w3 = ew[(size_t)(e+3)*4 + h];
      float4 f0 = feat4[(size_t)s0*40 + lane];
      float4 f1 = feat4[(size_t)s1*40 + lane];
      float4 f2 = feat4[(size_t)s2*40 + lane];
      float4 f3 = feat4[(size_t)s3*40 + lane];
      acc0.x = fmaf(w0,f0.x,acc0.x); acc0.y = fmaf(w0,f0.y,acc0.y);
      acc0.z = fmaf(w0,f0.z,acc0.z); acc0.w = fmaf(w0,f0.w,acc0.w); den0 += w0;
      acc1.x = fmaf(w1,f1.x,acc1.x); acc1.y = fmaf(w1,f1.y,acc1.y);
      acc1.z = fmaf(w1,f1.z,acc1.z); acc1.w = fmaf(w1,f1.w,acc1.w); den1 += w1;
      acc2.x = fmaf(w2,f2.x,acc2.x); acc2.y = fmaf(w2,f2.y,acc2.y);
      acc2.z = fmaf(w2,f2.z,acc2.z); acc2.w = fmaf(w2,f2.w,acc2.w); den2 += w2;
      acc3.x = fmaf(w3,f3.x,acc3.x); acc3.y = fmaf(w3,f3.y,acc3.y);
      acc3.z = fmaf(w3,f3.z,acc3.z); acc3.w = fmaf(w3,f3.w,acc3.w); den3 += w3;
    }
    for(; e < e1; e++){
      int s = ssrc[e];
      float w = ew[(size_t)e*4 + h];
      float4 f = feat4[(size_t)s*40 + lane];
      acc0.x = fmaf(w,f.x,acc0.x); acc0.y = fmaf(w,f.y,acc0.y);
      acc0.z = fmaf(w,f.z,acc0.z); acc0.w = fmaf(w,f.w,acc0.w); den0 += w;
    }
    float denom = (den0+den1) + (den2+den3);
    float4 acc;
    acc.x = (acc0.x+acc1.x) + (acc2.x+acc3.x);
    acc.y = (acc0.y+acc1.y) + (acc2.y+acc3.y);
    acc.z = (acc0.z+acc1.z) + (acc2.z+acc3.z);
    acc.w = (acc0.w+acc1.w) + (acc2.w+acc3.w);
    float inv = 1.f / fmaxf(denom, 1e-9f);
    float4 b4 = *(const float4*)&bias[lane*4];
    s_out[wv][lane*4+0] = acc.x*inv + b4.x;
    s_out[wv][lane*4+1] = acc.y*inv + b4.y;
    s_out[wv][lane*4+2] = acc.z*inv + b4.z;
    s_out[wv][lane*4+3] = acc.w*inv + b4.w;
  }
  __syncthreads();
  if(valid && lane < 40){
    logits[(size_t)n*40 + lane] =
        0.25f * (s_out[wv][lane] + s_out[wv][40+lane] + s_out[wv][80+lane] + s_out[wv][120+lane]);
  }
}

extern "C" void kernel_launch(void* const* d_in, const int* in_sizes, int n_in,
                              void* d_out, int out_size, void* d_ws, size_t ws_size,
                              hipStream_t stream){
  const float* x   = (const float*)d_in[0];
  const int*   eix = (const int*)  d_in[1];
  const float* W0  = (const float*)d_in[2];
  const float* al0 = (const float*)d_in[3];
  const float* ar0 = (const float*)d_in[4];
  const float* b0  = (const float*)d_in[5];
  const float* W1  = (const float*)d_in[6];
  const float* al1 = (const float*)d_in[7];
  const float* ar1 = (const float*)d_in[8];
  const float* b1  = (const float*)d_in[9];
  const float* W2  = (const float*)d_in[10];
  const float* al2 = (const float*)d_in[11];
  const float* ar2 = (const float*)d_in[12];
  const float* b2  = (const float*)d_in[13];
  float* logits = (float*)d_out;

  const int N = in_sizes[0] / 256;   // 50000
  const int E = in_sizes[1] / 2;     // 800000
  const int* src = eix;
  const int* dst = eix + E;

  char* ws = (char*)d_ws;
  auto alloc = [&](size_t bytes)->char*{
    char* p = ws; ws += (bytes + 255) & ~(size_t)255; return p;
  };
  int*   counts  = (int*)  alloc((size_t)N*4);
  int*   offsets = (int*)  alloc((size_t)(N+1)*4);
  int*   cursor  = (int*)  alloc((size_t)N*4);
  int*   ssrc    = (int*)  alloc((size_t)E*4);
  int*   sdst    = (int*)  alloc((size_t)E*4);
  float* ew      = (float*)alloc((size_t)E*4*4);
  float* bufF    = (float*)alloc((size_t)N*256*4);
  float* bufH    = (float*)alloc((size_t)N*256*4);
  float* el_buf  = (float*)alloc((size_t)N*4*4);
  float* er_buf  = (float*)alloc((size_t)N*4*4);

  // sort edges by dst (graph fixed across layers — one sort per call)
  hipMemsetAsync(counts, 0, (size_t)N*4, stream);
  hist_kernel   <<<(E+255)/256, 256, 0, stream>>>(dst, E, counts);
  scan_kernel   <<<1, 1024, 0, stream>>>(counts, N, offsets, cursor);
  scatter_kernel<<<(E+255)/256, 256, 0, stream>>>(src, dst, E, cursor, ssrc, sdst);

  dim3 g01(256/64, (N+127)/128);
  int aggGrid = (N+3)/4;
  int ewGrid  = (E+255)/256;
  // layer 0
  gemm128  <<<g01, 256, 0, stream>>>(x, W0, bufF, N, 256, 256);
  attn_proj<<<N, 256, 0, stream>>>(bufF, al0, ar0, el_buf, er_buf, 64);
  edge_w_kernel<<<ewGrid, 256, 0, stream>>>(ssrc, sdst, E, (const float4*)el_buf, (const float4*)er_buf, (float4*)ew);
  agg_kernel<<<aggGrid, 256, 0, stream>>>((const float4*)bufF, ew, offsets, ssrc, b0, bufH, N);
  // layer 1
  gemm128  <<<g01, 256, 0, stream>>>(bufH, W1, bufF, N, 256, 256);
  attn_proj<<<N, 256, 0, stream>>>(bufF, al1, ar1, el_buf, er_buf, 64);
  edge_w_kernel<<<ewGrid, 256, 0, stream>>>(ssrc, sdst, E, (const float4*)el_buf, (const float4*)er_buf, (float4*)ew);
  agg_kernel<<<aggGrid, 256, 0, stream>>>((const float4*)bufF, ew, offsets, ssrc, b1, bufH, N);
  // layer 2
  dim3 g2((160+63)/64, (N+127)/128);
  gemm128  <<<g2, 256, 0, stream>>>(bufH, W2, bufF, N, 160, 256);
  attn_proj<<<N, 256, 0, stream>>>(bufF, al2, ar2, el_buf, er_buf, 40);
  edge_w_kernel<<<ewGrid, 256, 0, stream>>>(ssrc, sdst, E, (const float4*)el_buf, (const float4*)er_buf, (float4*)ew);
  agg2_kernel<<<aggGrid, 256, 0, stream>>>((const float4*)bufF, ew, offsets, ssrc, b2, logits, N);
}

// Round 4
// 694.526 us; speedup vs baseline: 1.6278x; 1.3607x over previous
//
#include <hip/hip_runtime.h>
#include <hip/hip_bf16.h>
#include <math.h>

#define NEG_SLOPE 0.2f

static __device__ __forceinline__ float leaky(float x){ return x > 0.f ? x : NEG_SLOPE * x; }
static __device__ __forceinline__ float elu(float x){ return x > 0.f ? x : (__expf(x) - 1.f); }

// bf16 helpers: RNE pack, exact unpack
static __device__ __forceinline__ unsigned short f2bf(float f){
  unsigned u = __float_as_uint(f);
  u += 0x7fff + ((u >> 16) & 1);
  return (unsigned short)(u >> 16);
}
static __device__ __forceinline__ float bf_lo(unsigned u){ return __uint_as_float(u << 16); }
static __device__ __forceinline__ float bf_hi(unsigned u){ return __uint_as_float(u & 0xffff0000u); }

// ---------------- edge sort by dst (counting sort) ----------------
__global__ void hist_kernel(const int* __restrict__ dst, int E, int* __restrict__ counts){
  int i = blockIdx.x*blockDim.x + threadIdx.x;
  if(i < E) atomicAdd(&counts[dst[i]], 1);
}

// 3-phase parallel exclusive scan over counts[N]
__global__ void scan1_kernel(const int* __restrict__ counts, int N,
                             int* __restrict__ offsets, int* __restrict__ blocksums){
  __shared__ int sdata[1024];
  int i = blockIdx.x*1024 + threadIdx.x;
  int v = (i<N) ? counts[i] : 0;
  sdata[threadIdx.x] = v;
  __syncthreads();
  for(int off=1; off<1024; off<<=1){
    int t = (threadIdx.x >= off) ? sdata[threadIdx.x-off] : 0;
    __syncthreads();
    sdata[threadIdx.x] += t;
    __syncthreads();
  }
  if(i<N) offsets[i] = sdata[threadIdx.x] - v;           // block-local exclusive
  if(threadIdx.x==1023) blocksums[blockIdx.x] = sdata[1023];
}

__global__ void scan2_kernel(int* __restrict__ blocksums, int nb){
  __shared__ int sdata[64];
  int v = ((int)threadIdx.x < nb) ? blocksums[threadIdx.x] : 0;
  sdata[threadIdx.x] = v;
  __syncthreads();
  for(int off=1; off<64; off<<=1){
    int t = (threadIdx.x >= off) ? sdata[threadIdx.x-off] : 0;
    __syncthreads();
    sdata[threadIdx.x] += t;
    __syncthreads();
  }
  if((int)threadIdx.x < nb) blocksums[threadIdx.x] = sdata[threadIdx.x] - v;  // exclusive base
}

__global__ void scan3_kernel(int* __restrict__ offsets, const int* __restrict__ blocksums,
                             int N, int E, int* __restrict__ cursor){
  int i = blockIdx.x*1024 + threadIdx.x;
  if(i < N){
    int o = offsets[i] + blocksums[blockIdx.x];
    offsets[i] = o;
    cursor[i] = o;
  }
  if(i == 0) offsets[N] = E;
}

__global__ void scatter_kernel(const int* __restrict__ src, const int* __restrict__ dst, int E,
                               int* __restrict__ cursor, int* __restrict__ ssrc,
                               int* __restrict__ sdst){
  int i = blockIdx.x*blockDim.x + threadIdx.x;
  if(i < E){
    int d = dst[i];
    int p = atomicAdd(&cursor[d], 1);
    ssrc[p] = src[i];
    sdst[p] = d;
  }
}

// ---------------- per-edge softmax numerators (all 4 heads) ----------------
__global__ __launch_bounds__(256) void edge_w_kernel(const int* __restrict__ ssrc,
                              const int* __restrict__ sdst, int E,
                              const float4* __restrict__ el4, const float4* __restrict__ er4,
                              float4* __restrict__ ew){
  int e = blockIdx.x*blockDim.x + threadIdx.x;
  if(e >= E) return;
  int s = ssrc[e], d = sdst[e];
  float4 l = el4[s], r = er4[d];
  float4 w;
  w.x = __expf(leaky(l.x + r.x));
  w.y = __expf(leaky(l.y + r.y));
  w.z = __expf(leaky(l.z + r.z));
  w.w = __expf(leaky(l.w + r.w));
  ew[e] = w;
}

// ---------------- fp32 tiled GEMM, bf16 output: C[M,N] = A[M,K] @ B[K,N] ----------------
// tile 128x64, 256 threads, each thread 8x4, K-step 16.
// If al != nullptr (layers 0/1, N==256): the 64-wide n-tile is exactly head h = n0>>6;
// fused epilogue computes el/er from the fp32 registers (pre-rounding — closer to ref).
__global__ __launch_bounds__(256) void gemm128(const float* __restrict__ A, const float* __restrict__ B,
                       __hip_bfloat16* __restrict__ Cm, int M, int N, int K,
                       const float* __restrict__ al, const float* __restrict__ ar,
                       float* __restrict__ el, float* __restrict__ er){
  __shared__ float As[16][128];   // [k][m]
  __shared__ float Bs[16][64];    // [k][n]
  const int tid = threadIdx.x;
  const int tx = tid & 15;
  const int ty = tid >> 4;
  const int m0 = blockIdx.y * 128;
  const int n0 = blockIdx.x * 64;
  const int arow = tid >> 1;           // 0..127
  const int aq   = (tid & 1) * 8;      // k-offset 0 or 8
  const int bk   = tid >> 4;           // 0..15
  const int bn   = (tid & 15) * 4;
  float acc[8][4] = {};
  for(int k0=0; k0<K; k0+=16){
    float4 a0 = make_float4(0.f,0.f,0.f,0.f), a1 = a0;
    int gm = m0 + arow;
    if(gm < M){
      a0 = *(const float4*)&A[(size_t)gm*K + k0 + aq];
      a1 = *(const float4*)&A[(size_t)gm*K + k0 + aq + 4];
    }
    As[aq+0][arow]=a0.x; As[aq+1][arow]=a0.y; As[aq+2][arow]=a0.z; As[aq+3][arow]=a0.w;
    As[aq+4][arow]=a1.x; As[aq+5][arow]=a1.y; As[aq+6][arow]=a1.z; As[aq+7][arow]=a1.w;
    float4 bv = make_float4(0.f,0.f,0.f,0.f);
    int gn = n0 + bn;
    const float* brow = &B[(size_t)(k0+bk)*N];
    if(gn + 3 < N) bv = *(const float4*)&brow[gn];
    else {
      if(gn   < N) bv.x = brow[gn];
      if(gn+1 < N) bv.y = brow[gn+1];
      if(gn+2 < N) bv.z = brow[gn+2];
    }
    *(float4*)&Bs[bk][bn] = bv;
    __syncthreads();
    #pragma unroll
    for(int k=0;k<16;k++){
      float4 b4  = *(const float4*)&Bs[k][tx*4];
      float4 a04 = *(const float4*)&As[k][ty*8];
      float4 a14 = *(const float4*)&As[k][ty*8+4];
      float aa[8] = {a04.x,a04.y,a04.z,a04.w,a14.x,a14.y,a14.z,a14.w};
      float bb[4] = {b4.x,b4.y,b4.z,b4.w};
      #pragma unroll
      for(int i=0;i<8;i++)
        #pragma unroll
        for(int j=0;j<4;j++)
          acc[i][j] = fmaf(aa[i], bb[j], acc[i][j]);
    }
    __syncthreads();
  }
  // fused el/er (layers 0/1): reduce over the 16 tx-lanes of each row group
  if(al){
    const int h = n0 >> 6;
    float4 alv = *(const float4*)&al[(h<<6) + tx*4];
    float4 arv = *(const float4*)&ar[(h<<6) + tx*4];
    #pragma unroll
    for(int i=0;i<8;i++){
      float pl = acc[i][0]*alv.x + acc[i][1]*alv.y + acc[i][2]*alv.z + acc[i][3]*alv.w;
      float pr = acc[i][0]*arv.x + acc[i][1]*arv.y + acc[i][2]*arv.z + acc[i][3]*arv.w;
      #pragma unroll
      for(int off=8; off; off>>=1){ pl += __shfl_down(pl,off); pr += __shfl_down(pr,off); }
      if(tx==0){
        int gm = m0 + ty*8 + i;
        if(gm < M){ el[gm*4+h] = pl; er[gm*4+h] = pr; }
      }
    }
  }
  #pragma unroll
  for(int i=0;i<8;i++){
    int gm = m0 + ty*8 + i;
    if(gm >= M) continue;
    int gn = n0 + tx*4;
    if(gn + 3 < N){
      ushort4 o;
      o.x = f2bf(acc[i][0]); o.y = f2bf(acc[i][1]);
      o.z = f2bf(acc[i][2]); o.w = f2bf(acc[i][3]);
      *(ushort4*)&Cm[(size_t)gm*N + gn] = o;
    } else {
      #pragma unroll
      for(int j=0;j<4;j++) if(gn+j < N) Cm[(size_t)gm*N + gn + j] = __hip_bfloat16(acc[i][j]);
    }
  }
}

// ---------------- el/er projection from bf16 feat (layer 2 only) ----------------
__global__ void attn_proj_bf(const __hip_bfloat16* __restrict__ feat, const float* __restrict__ a_l,
                             const float* __restrict__ a_r, float* __restrict__ el,
                             float* __restrict__ er, int D){
  int n = blockIdx.x;
  int h = threadIdx.x >> 6;
  int lane = threadIdx.x & 63;
  float vl = 0.f, vr = 0.f;
  for(int d=lane; d<D; d+=64){
    float f = (float)feat[(size_t)n*4*D + h*D + d];
    vl = fmaf(f, a_l[h*D+d], vl);
    vr = fmaf(f, a_r[h*D+d], vr);
  }
  #pragma unroll
  for(int off=32; off; off>>=1){ vl += __shfl_down(vl,off); vr += __shfl_down(vr,off); }
  if(lane==0){ el[n*4+h] = vl; er[n*4+h] = vr; }
}

// ---------------- softmax + aggregate, layers 0/1 (H*D=256 bf16), ELU ----------------
// one WAVE per dst node; lane holds 4 bf16 (8 B) of the 512 B row; x4 unroll for MLP
__global__ __launch_bounds__(256) void agg_kernel(const uint2* __restrict__ feat2,
                           const float* __restrict__ ew,
                           const int* __restrict__ offsets, const int* __restrict__ ssrc,
                           const float* __restrict__ bias, float* __restrict__ outp, int N){
  int wv = threadIdx.x >> 6;
  int lane = threadIdx.x & 63;
  int n = blockIdx.x*4 + wv;
  if(n >= N) return;
  int h = lane >> 4;                 // cols lane*4..+3 all in head lane>>4
  int e0 = offsets[n], e1 = offsets[n+1];
  float4 acc0 = make_float4(0.f,0.f,0.f,0.f), acc1 = acc0, acc2 = acc0, acc3 = acc0;
  float den0 = 0.f, den1 = 0.f, den2 = 0.f, den3 = 0.f;
  int e = e0;
  for(; e+3 < e1; e += 4){
    int s0 = ssrc[e], s1 = ssrc[e+1], s2 = ssrc[e+2], s3 = ssrc[e+3];
    float w0 = ew[(size_t)e*4 + h];
    float w1 = ew[(size_t)(e+1)*4 + h];
    float w2 = ew[(size_t)(e+2)*4 + h];
    float w3 = ew[(size_t)(e+3)*4 + h];
    uint2 q0 = feat2[(size_t)s0*64 + lane];
    uint2 q1 = feat2[(size_t)s1*64 + lane];
    uint2 q2 = feat2[(size_t)s2*64 + lane];
    uint2 q3 = feat2[(size_t)s3*64 + lane];
    acc0.x = fmaf(w0,bf_lo(q0.x),acc0.x); acc0.y = fmaf(w0,bf_hi(q0.x),acc0.y);
    acc0.z = fmaf(w0,bf_lo(q0.y),acc0.z); acc0.w = fmaf(w0,bf_hi(q0.y),acc0.w); den0 += w0;
    acc1.x = fmaf(w1,bf_lo(q1.x),acc1.x); acc1.y = fmaf(w1,bf_hi(q1.x),acc1.y);
    acc1.z = fmaf(w1,bf_lo(q1.y),acc1.z); acc1.w = fmaf(w1,bf_hi(q1.y),acc1.w); den1 += w1;
    acc2.x = fmaf(w2,bf_lo(q2.x),acc2.x); acc2.y = fmaf(w2,bf_hi(q2.x),acc2.y);
    acc2.z = fmaf(w2,bf_lo(q2.y),acc2.z); acc2.w = fmaf(w2,bf_hi(q2.y),acc2.w); den2 += w2;
    acc3.x = fmaf(w3,bf_lo(q3.x),acc3.x); acc3.y = fmaf(w3,bf_hi(q3.x),acc3.y);
    acc3.z = fmaf(w3,bf_lo(q3.y),acc3.z); acc3.w = fmaf(w3,bf_hi(q3.y),acc3.w); den3 += w3;
  }
  for(; e < e1; e++){
    int s = ssrc[e];
    float w = ew[(size_t)e*4 + h];
    uint2 q = feat2[(size_t)s*64 + lane];
    acc0.x = fmaf(w,bf_lo(q.x),acc0.x); acc0.y = fmaf(w,bf_hi(q.x),acc0.y);
    acc0.z = fmaf(w,bf_lo(q.y),acc0.z); acc0.w = fmaf(w,bf_hi(q.y),acc0.w); den0 += w;
  }
  float denom = (den0+den1) + (den2+den3);
  float4 acc;
  acc.x = (acc0.x+acc1.x) + (acc2.x+acc3.x);
  acc.y = (acc0.y+acc1.y) + (acc2.y+acc3.y);
  acc.z = (acc0.z+acc1.z) + (acc2.z+acc3.z);
  acc.w = (acc0.w+acc1.w) + (acc2.w+acc3.w);
  float inv = 1.f / fmaxf(denom, 1e-9f);
  float4 b4 = *(const float4*)&bias[lane*4];
  float4 o;
  o.x = elu(acc.x*inv + b4.x);
  o.y = elu(acc.y*inv + b4.y);
  o.z = elu(acc.z*inv + b4.z);
  o.w = elu(acc.w*inv + b4.w);
  *(float4*)&outp[(size_t)n*256 + lane*4] = o;
}

// ---------------- layer 2: aggregate (H*C=160 bf16) + head-mean logits ----------------
__global__ __launch_bounds__(256) void agg2_kernel(const uint2* __restrict__ feat2,
                            const float* __restrict__ ew,
                            const int* __restrict__ offsets, const int* __restrict__ ssrc,
                            const float* __restrict__ bias, float* __restrict__ logits, int N){
  __shared__ float s_out[4][160];
  int wv = threadIdx.x >> 6;
  int lane = threadIdx.x & 63;
  int n = blockIdx.x*4 + wv;
  bool valid = (n < N);
  if(valid && lane < 40){
    int h = lane / 10;
    int e0 = offsets[n], e1 = offsets[n+1];
    float4 acc0 = make_float4(0.f,0.f,0.f,0.f), acc1 = acc0, acc2 = acc0, acc3 = acc0;
    float den0 = 0.f, den1 = 0.f, den2 = 0.f, den3 = 0.f;
    int e = e0;
    for(; e+3 < e1; e += 4){
      int s0 = ssrc[e], s1 = ssrc[e+1], s2 = ssrc[e+2], s3 = ssrc[e+3];
      float w0 = ew[(size_t)e*4 + h];
      float w1 = ew[(size_t)(e+1)*4 + h];
      float w2 = ew[(size_t)(e+2)*4 + h];
      float w3 = ew[(size_t)(e+3)*4 + h];
      uint2 q0 = feat2[(size_t)s0*40 + lane];
      uint2 q1 = feat2[(size_t)s1*40 + lane];
      uint2 q2 = feat2[(size_t)s2*40 + lane];
      uint2 q3 = feat2[(size_t)s3*40 + lane];
      acc0.x = fmaf(w0,bf_lo(q0.x),acc0.x); acc0.y = fmaf(w0,bf_hi(q0.x),acc0.y);
      acc0.z = fmaf(w0,bf_lo(q0.y),acc0.z); acc0.w = fmaf(w0,bf_hi(q0.y),acc0.w); den0 += w0;
      acc1.x = fmaf(w1,bf_lo(q1.x),acc1.x); acc1.y = fmaf(w1,bf_hi(q1.x),acc1.y);
      acc1.z = fmaf(w1,bf_lo(q1.y),acc1.z); acc1.w = fmaf(w1,bf_hi(q1.y),acc1.w); den1 += w1;
      acc2.x = fmaf(w2,bf_lo(q2.x),acc2.x); acc2.y = fmaf(w2,bf_hi(q2.x),acc2.y);
      acc2.z = fmaf(w2,bf_lo(q2.y),acc2.z); acc2.w = fmaf(w2,bf_hi(q2.y),acc2.w); den2 += w2;
      acc3.x = fmaf(w3,bf_lo(q3.x),acc3.x); acc3.y = fmaf(w3,bf_hi(q3.x),acc3.y);
      acc3.z = fmaf(w3,bf_lo(q3.y),acc3.z); acc3.w = fmaf(w3,bf_hi(q3.y),acc3.w); den3 += w3;
    }
    for(; e < e1; e++){
      int s = ssrc[e];
      float w = ew[(size_t)e*4 + h];
      uint2 q = feat2[(size_t)s*40 + lane];
      acc0.x = fmaf(w,bf_lo(q.x),acc0.x); acc0.y = fmaf(w,bf_hi(q.x),acc0.y);
      acc0.z = fmaf(w,bf_lo(q.y),acc0.z); acc0.w = fmaf(w,bf_hi(q.y),acc0.w); den0 += w;
    }
    float denom = (den0+den1) + (den2+den3);
    float4 acc;
    acc.x = (acc0.x+acc1.x) + (acc2.x+acc3.x);
    acc.y = (acc0.y+acc1.y) + (acc2.y+acc3.y);
    acc.z = (acc0.z+acc1.z) + (acc2.z+acc3.z);
    acc.w = (acc0.w+acc1.w) + (acc2.w+acc3.w);
    float inv = 1.f / fmaxf(denom, 1e-9f);
    float4 b4 = *(const float4*)&bias[lane*4];
    s_out[wv][lane*4+0] = acc.x*inv + b4.x;
    s_out[wv][lane*4+1] = acc.y*inv + b4.y;
    s_out[wv][lane*4+2] = acc.z*inv + b4.z;
    s_out[wv][lane*4+3] = acc.w*inv + b4.w;
  }
  __syncthreads();
  if(valid && lane < 40){
    logits[(size_t)n*40 + lane] =
        0.25f * (s_out[wv][lane] + s_out[wv][40+lane] + s_out[wv][80+lane] + s_out[wv][120+lane]);
  }
}

extern "C" void kernel_launch(void* const* d_in, const int* in_sizes, int n_in,
                              void* d_out, int out_size, void* d_ws, size_t ws_size,
                              hipStream_t stream){
  const float* x   = (const float*)d_in[0];
  const int*   eix = (const int*)  d_in[1];
  const float* W0  = (const float*)d_in[2];
  const float* al0 = (const float*)d_in[3];
  const float* ar0 = (const float*)d_in[4];
  const float* b0  = (const float*)d_in[5];
  const float* W1  = (const float*)d_in[6];
  const float* al1 = (const float*)d_in[7];
  const float* ar1 = (const float*)d_in[8];
  const float* b1  = (const float*)d_in[9];
  const float* W2  = (const float*)d_in[10];
  const float* al2 = (const float*)d_in[11];
  const float* ar2 = (const float*)d_in[12];
  const float* b2  = (const float*)d_in[13];
  float* logits = (float*)d_out;

  const int N = in_sizes[0] / 256;   // 50000
  const int E = in_sizes[1] / 2;     // 800000
  const int* src = eix;
  const int* dst = eix + E;
  const int nb = (N + 1023) / 1024;  // scan blocks

  char* ws = (char*)d_ws;
  auto alloc = [&](size_t bytes)->char*{
    char* p = ws; ws += (bytes + 255) & ~(size_t)255; return p;
  };
  int*   counts    = (int*)  alloc((size_t)N*4);
  int*   offsets   = (int*)  alloc((size_t)(N+1)*4);
  int*   cursor    = (int*)  alloc((size_t)N*4);
  int*   blocksums = (int*)  alloc((size_t)nb*4);
  int*   ssrc      = (int*)  alloc((size_t)E*4);
  int*   sdst      = (int*)  alloc((size_t)E*4);
  float* ew        = (float*)alloc((size_t)E*4*4);
  __hip_bfloat16* bufF = (__hip_bfloat16*)alloc((size_t)N*256*2);   // bf16 feat
  float* bufH      = (float*)alloc((size_t)N*256*4);                 // fp32 layer output
  float* el_buf    = (float*)alloc((size_t)N*4*4);
  float* er_buf    = (float*)alloc((size_t)N*4*4);

  // sort edges by dst (graph fixed across layers — one sort per call)
  hipMemsetAsync(counts, 0, (size_t)N*4, stream);
  hist_kernel   <<<(E+255)/256, 256, 0, stream>>>(dst, E, counts);
  scan1_kernel  <<<nb, 1024, 0, stream>>>(counts, N, offsets, blocksums);
  scan2_kernel  <<<1, 64, 0, stream>>>(blocksums, nb);
  scan3_kernel  <<<nb, 1024, 0, stream>>>(offsets, blocksums, N, E, cursor);
  scatter_kernel<<<(E+255)/256, 256, 0, stream>>>(src, dst, E, cursor, ssrc, sdst);

  dim3 g01(256/64, (N+127)/128);
  int aggGrid = (N+3)/4;
  int ewGrid  = (E+255)/256;
  // layer 0 (el/er fused into GEMM epilogue)
  gemm128  <<<g01, 256, 0, stream>>>(x, W0, bufF, N, 256, 256, al0, ar0, el_buf, er_buf);
  edge_w_kernel<<<ewGrid, 256, 0, stream>>>(ssrc, sdst, E, (const float4*)el_buf, (const float4*)er_buf, (float4*)ew);
  agg_kernel<<<aggGrid, 256, 0, stream>>>((const uint2*)bufF, ew, offsets, ssrc, b0, bufH, N);
  // layer 1
  gemm128  <<<g01, 256, 0, stream>>>(bufH, W1, bufF, N, 256, 256, al1, ar1, el_buf, er_buf);
  edge_w_kernel<<<ewGrid, 256, 0, stream>>>(ssrc, sdst, E, (const float4*)el_buf, (const float4*)er_buf, (float4*)ew);
  agg_kernel<<<aggGrid, 256, 0, stream>>>((const uint2*)bufF, ew, offsets, ssrc, b1, bufH, N);
  // layer 2 (N=160: no fusion; separate bf16 attn_proj)
  dim3 g2((160+63)/64, (N+127)/128);
  gemm128  <<<g2, 256, 0, stream>>>(bufH, W2, bufF, N, 160, 256, nullptr, nullptr, nullptr, nullptr);
  attn_proj_bf<<<N, 256, 0, stream>>>(bufF, al2, ar2, el_buf, er_buf, 40);
  edge_w_kernel<<<ewGrid, 256, 0, stream>>>(ssrc, sdst, E, (const float4*)el_buf, (const float4*)er_buf, (float4*)ew);
  agg2_kernel<<<aggGrid, 256, 0, stream>>>((const uint2*)bufF, ew, offsets, ssrc, b2, logits, N);
}

// Round 6
// 636.346 us; speedup vs baseline: 1.7766x; 1.0914x over previous
//
#include <hip/hip_runtime.h>
#include <hip/hip_bf16.h>
#include <math.h>

#define NEG_SLOPE 0.2f

typedef unsigned short ushortT;
typedef __attribute__((ext_vector_type(8))) short short8;   // 8 bf16 = 4 VGPRs (MFMA A/B frag)
typedef __attribute__((ext_vector_type(4))) float f32x4;    // MFMA C/D frag

static __device__ __forceinline__ float leaky(float x){ return x > 0.f ? x : NEG_SLOPE * x; }
static __device__ __forceinline__ float elu(float x){ return x > 0.f ? x : (__expf(x) - 1.f); }

// bf16 helpers: RNE pack, exact unpack
static __device__ __forceinline__ ushortT f2bf(float f){
  unsigned u = __float_as_uint(f);
  u += 0x7fff + ((u >> 16) & 1);
  return (ushortT)(u >> 16);
}
static __device__ __forceinline__ float bf2f(ushortT h){ return __uint_as_float((unsigned)h << 16); }
static __device__ __forceinline__ float bf_lo(unsigned u){ return __uint_as_float(u << 16); }
static __device__ __forceinline__ float bf_hi(unsigned u){ return __uint_as_float(u & 0xffff0000u); }

// ---------------- edge sort by dst (counting sort) ----------------
__global__ void hist_kernel(const int* __restrict__ dst, int E, int* __restrict__ counts){
  int i = blockIdx.x*blockDim.x + threadIdx.x;
  if(i < E) atomicAdd(&counts[dst[i]], 1);
}

__global__ void scan1_kernel(const int* __restrict__ counts, int N,
                             int* __restrict__ offsets, int* __restrict__ blocksums){
  __shared__ int sdata[1024];
  int i = blockIdx.x*1024 + threadIdx.x;
  int v = (i<N) ? counts[i] : 0;
  sdata[threadIdx.x] = v;
  __syncthreads();
  for(int off=1; off<1024; off<<=1){
    int t = (threadIdx.x >= off) ? sdata[threadIdx.x-off] : 0;
    __syncthreads();
    sdata[threadIdx.x] += t;
    __syncthreads();
  }
  if(i<N) offsets[i] = sdata[threadIdx.x] - v;
  if(threadIdx.x==1023) blocksums[blockIdx.x] = sdata[1023];
}

__global__ void scan2_kernel(int* __restrict__ blocksums, int nb){
  __shared__ int sdata[64];
  int v = ((int)threadIdx.x < nb) ? blocksums[threadIdx.x] : 0;
  sdata[threadIdx.x] = v;
  __syncthreads();
  for(int off=1; off<64; off<<=1){
    int t = (threadIdx.x >= off) ? sdata[threadIdx.x-off] : 0;
    __syncthreads();
    sdata[threadIdx.x] += t;
    __syncthreads();
  }
  if((int)threadIdx.x < nb) blocksums[threadIdx.x] = sdata[threadIdx.x] - v;
}

__global__ void scan3_kernel(int* __restrict__ offsets, const int* __restrict__ blocksums,
                             int N, int E, int* __restrict__ cursor){
  int i = blockIdx.x*1024 + threadIdx.x;
  if(i < N){
    int o = offsets[i] + blocksums[blockIdx.x];
    offsets[i] = o;
    cursor[i] = o;
  }
  if(i == 0) offsets[N] = E;
}

__global__ void scatter_kernel(const int* __restrict__ src, const int* __restrict__ dst, int E,
                               int* __restrict__ cursor, int* __restrict__ ssrc,
                               int* __restrict__ sdst){
  int i = blockIdx.x*blockDim.x + threadIdx.x;
  if(i < E){
    int d = dst[i];
    int p = atomicAdd(&cursor[d], 1);
    ssrc[p] = src[i];
    sdst[p] = d;
  }
}

// ---------------- W pre-transpose + bf16 hi/lo split: W[K,N] -> Wt[Npad][K] ----------------
__global__ __launch_bounds__(256) void wsplit_kernel(const float* __restrict__ W, int N,
                              ushortT* __restrict__ Wth, ushortT* __restrict__ Wtl){
  int idx = blockIdx.x*256 + threadIdx.x;   // over 256*256
  int n = idx >> 8, k = idx & 255;
  float v = (n < N) ? W[(size_t)k*N + n] : 0.f;
  ushortT h = f2bf(v);
  ushortT l = f2bf(v - bf2f(h));
  Wth[idx] = h; Wtl[idx] = l;
}

// ---------------- bf16x3 MFMA GEMM: C[M,N] = A[M,K] @ B[K,N], bf16 out ----------------
// A fp32 row-major (split on the fly); B pre-split as Bt_hi/lo [256][K] bf16 (n-major).
// Block tile 128x128, 256 thr = 4 waves (2x2), each wave 64x64 = 4x4 frags of 16x16x32.
// LDS row stride 40 ushorts (80 B): 16B-aligned b128 frag reads, 2-way bank alias (free).
#define GBM 128
#define GBN 128
#define GBK 32
#define LSTR 40
__global__ __launch_bounds__(256) void gemm_mfma(const float* __restrict__ A,
                       const ushortT* __restrict__ Bth, const ushortT* __restrict__ Btl,
                       ushortT* __restrict__ Cm, int M, int N, int K){
  __shared__ ushortT Ah[GBM*LSTR], Al[GBM*LSTR], Bh[GBN*LSTR], Bl[GBN*LSTR];
  const int tid  = threadIdx.x;
  const int lane = tid & 63;
  const int wv   = tid >> 6;
  const int wr   = wv >> 1, wc = wv & 1;
  const int m0   = blockIdx.y * GBM;
  const int n0   = blockIdx.x * GBN;
  const int l15  = lane & 15, quad = lane >> 4;

  f32x4 acc[4][4];
  #pragma unroll
  for(int i=0;i<4;i++)
    #pragma unroll
    for(int j=0;j<4;j++){ acc[i][j][0]=0.f; acc[i][j][1]=0.f; acc[i][j][2]=0.f; acc[i][j][3]=0.f; }

  for(int k0=0; k0<K; k0+=GBK){
    // --- stage A (fp32 -> hi/lo bf16), 128x32 tile ---
    #pragma unroll
    for(int i=0;i<4;i++){
      int r  = (tid>>3) + i*32;
      int cq = (tid&7)*4;
      float4 v = make_float4(0.f,0.f,0.f,0.f);
      int gm = m0 + r;
      if(gm < M) v = *(const float4*)&A[(size_t)gm*K + k0 + cq];
      ushortT h0=f2bf(v.x), h1=f2bf(v.y), h2=f2bf(v.z), h3=f2bf(v.w);
      ushort4 hv = make_ushort4(h0,h1,h2,h3);
      ushort4 lv = make_ushort4(f2bf(v.x-bf2f(h0)), f2bf(v.y-bf2f(h1)),
                                f2bf(v.z-bf2f(h2)), f2bf(v.w-bf2f(h3)));
      *(ushort4*)&Ah[r*LSTR + cq] = hv;
      *(ushort4*)&Al[r*LSTR + cq] = lv;
    }
    // --- stage B (pre-split bf16, n-major): 128 rows x 32 k ---
    // each thread covers 16 ushorts = TWO uint4 loads (uint4 = 8 ushorts!)
    {
      int n  = tid >> 1;
      int kh = (tid & 1) * 16;
      const ushortT* bhrow = &Bth[(size_t)(n0+n)*K + k0 + kh];
      const ushortT* blrow = &Btl[(size_t)(n0+n)*K + k0 + kh];
      uint4 hv0 = *(const uint4*)(bhrow);
      uint4 hv1 = *(const uint4*)(bhrow + 8);
      uint4 lv0 = *(const uint4*)(blrow);
      uint4 lv1 = *(const uint4*)(blrow + 8);
      *(uint4*)&Bh[n*LSTR + kh]     = hv0;
      *(uint4*)&Bh[n*LSTR + kh + 8] = hv1;
      *(uint4*)&Bl[n*LSTR + kh]     = lv0;
      *(uint4*)&Bl[n*LSTR + kh + 8] = lv1;
    }
    __syncthreads();
    // --- fragments ---
    short8 a_h[4], a_l[4], b_h[4], b_l[4];
    #pragma unroll
    for(int i=0;i<4;i++){
      int m = wr*64 + i*16 + l15;
      a_h[i] = *(short8*)&Ah[m*LSTR + quad*8];
      a_l[i] = *(short8*)&Al[m*LSTR + quad*8];
    }
    #pragma unroll
    for(int j=0;j<4;j++){
      int n = wc*64 + j*16 + l15;
      b_h[j] = *(short8*)&Bh[n*LSTR + quad*8];
      b_l[j] = *(short8*)&Bl[n*LSTR + quad*8];
    }
    #pragma unroll
    for(int i=0;i<4;i++)
      #pragma unroll
      for(int j=0;j<4;j++){
        acc[i][j] = __builtin_amdgcn_mfma_f32_16x16x32_bf16(a_h[i], b_h[j], acc[i][j], 0,0,0);
        acc[i][j] = __builtin_amdgcn_mfma_f32_16x16x32_bf16(a_h[i], b_l[j], acc[i][j], 0,0,0);
        acc[i][j] = __builtin_amdgcn_mfma_f32_16x16x32_bf16(a_l[i], b_h[j], acc[i][j], 0,0,0);
      }
    __syncthreads();
  }
  // --- epilogue: C/D layout col=lane&15, row=quad*4+r ---
  #pragma unroll
  for(int i=0;i<4;i++){
    #pragma unroll
    for(int r=0;r<4;r++){
      int gm = m0 + wr*64 + i*16 + quad*4 + r;
      if(gm >= M) continue;
      #pragma unroll
      for(int j=0;j<4;j++){
        int gn = n0 + wc*64 + j*16 + l15;
        if(gn < N) Cm[(size_t)gm*N + gn] = f2bf(acc[i][j][r]);
      }
    }
  }
}

// ---------------- el/er projection from bf16 feat ----------------
__global__ void attn_proj_bf(const __hip_bfloat16* __restrict__ feat, const float* __restrict__ a_l,
                             const float* __restrict__ a_r, float* __restrict__ el,
                             float* __restrict__ er, int D){
  int n = blockIdx.x;
  int h = threadIdx.x >> 6;
  int lane = threadIdx.x & 63;
  float vl = 0.f, vr = 0.f;
  for(int d=lane; d<D; d+=64){
    float f = (float)feat[(size_t)n*4*D + h*D + d];
    vl = fmaf(f, a_l[h*D+d], vl);
    vr = fmaf(f, a_r[h*D+d], vr);
  }
  #pragma unroll
  for(int off=32; off; off>>=1){ vl += __shfl_down(vl,off); vr += __shfl_down(vr,off); }
  if(lane==0){ el[n*4+h] = vl; er[n*4+h] = vr; }
}

// ---------------- per-edge softmax numerators (all 4 heads) ----------------
__global__ __launch_bounds__(256) void edge_w_kernel(const int* __restrict__ ssrc,
                              const int* __restrict__ sdst, int E,
                              const float4* __restrict__ el4, const float4* __restrict__ er4,
                              float4* __restrict__ ew){
  int e = blockIdx.x*blockDim.x + threadIdx.x;
  if(e >= E) return;
  int s = ssrc[e], d = sdst[e];
  float4 l = el4[s], r = er4[d];
  float4 w;
  w.x = __expf(leaky(l.x + r.x));
  w.y = __expf(leaky(l.y + r.y));
  w.z = __expf(leaky(l.z + r.z));
  w.w = __expf(leaky(l.w + r.w));
  ew[e] = w;
}

// ---------------- softmax + aggregate, layers 0/1 (H*D=256 bf16), ELU ----------------
__global__ __launch_bounds__(256) void agg_kernel(const uint2* __restrict__ feat2,
                           const float* __restrict__ ew,
                           const int* __restrict__ offsets, const int* __restrict__ ssrc,
                           const float* __restrict__ bias, float* __restrict__ outp, int N){
  int wv = threadIdx.x >> 6;
  int lane = threadIdx.x & 63;
  int n = blockIdx.x*4 + wv;
  if(n >= N) return;
  int h = lane >> 4;
  int e0 = offsets[n], e1 = offsets[n+1];
  float4 acc0 = make_float4(0.f,0.f,0.f,0.f), acc1 = acc0, acc2 = acc0, acc3 = acc0;
  float den0 = 0.f, den1 = 0.f, den2 = 0.f, den3 = 0.f;
  int e = e0;
  for(; e+3 < e1; e += 4){
    int s0 = ssrc[e], s1 = ssrc[e+1], s2 = ssrc[e+2], s3 = ssrc[e+3];
    float w0 = ew[(size_t)e*4 + h];
    float w1 = ew[(size_t)(e+1)*4 + h];
    float w2 = ew[(size_t)(e+2)*4 + h];
    float w3 = ew[(size_t)(e+3)*4 + h];
    uint2 q0 = feat2[(size_t)s0*64 + lane];
    uint2 q1 = feat2[(size_t)s1*64 + lane];
    uint2 q2 = feat2[(size_t)s2*64 + lane];
    uint2 q3 = feat2[(size_t)s3*64 + lane];
    acc0.x = fmaf(w0,bf_lo(q0.x),acc0.x); acc0.y = fmaf(w0,bf_hi(q0.x),acc0.y);
    acc0.z = fmaf(w0,bf_lo(q0.y),acc0.z); acc0.w = fmaf(w0,bf_hi(q0.y),acc0.w); den0 += w0;
    acc1.x = fmaf(w1,bf_lo(q1.x),acc1.x); acc1.y = fmaf(w1,bf_hi(q1.x),acc1.y);
    acc1.z = fmaf(w1,bf_lo(q1.y),acc1.z); acc1.w = fmaf(w1,bf_hi(q1.y),acc1.w); den1 += w1;
    acc2.x = fmaf(w2,bf_lo(q2.x),acc2.x); acc2.y = fmaf(w2,bf_hi(q2.x),acc2.y);
    acc2.z = fmaf(w2,bf_lo(q2.y),acc2.z); acc2.w = fmaf(w2,bf_hi(q2.y),acc2.w); den2 += w2;
    acc3.x = fmaf(w3,bf_lo(q3.x),acc3.x); acc3.y = fmaf(w3,bf_hi(q3.x),acc3.y);
    acc3.z = fmaf(w3,bf_lo(q3.y),acc3.z); acc3.w = fmaf(w3,bf_hi(q3.y),acc3.w); den3 += w3;
  }
  for(; e < e1; e++){
    int s = ssrc[e];
    float w = ew[(size_t)e*4 + h];
    uint2 q = feat2[(size_t)s*64 + lane];
    acc0.x = fmaf(w,bf_lo(q.x),acc0.x); acc0.y = fmaf(w,bf_hi(q.x),acc0.y);
    acc0.z = fmaf(w,bf_lo(q.y),acc0.z); acc0.w = fmaf(w,bf_hi(q.y),acc0.w); den0 += w;
  }
  float denom = (den0+den1) + (den2+den3);
  float4 acc;
  acc.x = (acc0.x+acc1.x) + (acc2.x+acc3.x);
  acc.y = (acc0.y+acc1.y) + (acc2.y+acc3.y);
  acc.z = (acc0.z+acc1.z) + (acc2.z+acc3.z);
  acc.w = (acc0.w+acc1.w) + (acc2.w+acc3.w);
  float inv = 1.f / fmaxf(denom, 1e-9f);
  float4 b4 = *(const float4*)&bias[lane*4];
  float4 o;
  o.x = elu(acc.x*inv + b4.x);
  o.y = elu(acc.y*inv + b4.y);
  o.z = elu(acc.z*inv + b4.z);
  o.w = elu(acc.w*inv + b4.w);
  *(float4*)&outp[(size_t)n*256 + lane*4] = o;
}

// ---------------- layer 2: aggregate (H*C=160 bf16) + head-mean logits ----------------
__global__ __launch_bounds__(256) void agg2_kernel(const uint2* __restrict__ feat2,
                            const float* __restrict__ ew,
                            const int* __restrict__ offsets, const int* __restrict__ ssrc,
                            const float* __restrict__ bias, float* __restrict__ logits, int N){
  __shared__ float s_out[4][160];
  int wv = threadIdx.x >> 6;
  int lane = threadIdx.x & 63;
  int n = blockIdx.x*4 + wv;
  bool valid = (n < N);
  if(valid && lane < 40){
    int h = lane / 10;
    int e0 = offsets[n], e1 = offsets[n+1];
    float4 acc0 = make_float4(0.f,0.f,0.f,0.f), acc1 = acc0, acc2 = acc0, acc3 = acc0;
    float den0 = 0.f, den1 = 0.f, den2 = 0.f, den3 = 0.f;
    int e = e0;
    for(; e+3 < e1; e += 4){
      int s0 = ssrc[e], s1 = ssrc[e+1], s2 = ssrc[e+2], s3 = ssrc[e+3];
      float w0 = ew[(size_t)e*4 + h];
      float w1 = ew[(size_t)(e+1)*4 + h];
      float w2 = ew[(size_t)(e+2)*4 + h];
      float w3 = ew[(size_t)(e+3)*4 + h];
      uint2 q0 = feat2[(size_t)s0*40 + lane];
      uint2 q1 = feat2[(size_t)s1*40 + lane];
      uint2 q2 = feat2[(size_t)s2*40 + lane];
      uint2 q3 = feat2[(size_t)s3*40 + lane];
      acc0.x = fmaf(w0,bf_lo(q0.x),acc0.x); acc0.y = fmaf(w0,bf_hi(q0.x),acc0.y);
      acc0.z = fmaf(w0,bf_lo(q0.y),acc0.z); acc0.w = fmaf(w0,bf_hi(q0.y),acc0.w); den0 += w0;
      acc1.x = fmaf(w1,bf_lo(q1.x),acc1.x); acc1.y = fmaf(w1,bf_hi(q1.x),acc1.y);
      acc1.z = fmaf(w1,bf_lo(q1.y),acc1.z); acc1.w = fmaf(w1,bf_hi(q1.y),acc1.w); den1 += w1;
      acc2.x = fmaf(w2,bf_lo(q2.x),acc2.x); acc2.y = fmaf(w2,bf_hi(q2.x),acc2.y);
      acc2.z = fmaf(w2,bf_lo(q2.y),acc2.z); acc2.w = fmaf(w2,bf_hi(q2.y),acc2.w); den2 += w2;
      acc3.x = fmaf(w3,bf_lo(q3.x),acc3.x); acc3.y = fmaf(w3,bf_hi(q3.x),acc3.y);
      acc3.z = fmaf(w3,bf_lo(q3.y),acc3.z); acc3.w = fmaf(w3,bf_hi(q3.y),acc3.w); den3 += w3;
    }
    for(; e < e1; e++){
      int s = ssrc[e];
      float w = ew[(size_t)e*4 + h];
      uint2 q = feat2[(size_t)s*40 + lane];
      acc0.x = fmaf(w,bf_lo(q.x),acc0.x); acc0.y = fmaf(w,bf_hi(q.x),acc0.y);
      acc0.z = fmaf(w,bf_lo(q.y),acc0.z); acc0.w = fmaf(w,bf_hi(q.y),acc0.w); den0 += w;
    }
    float denom = (den0+den1) + (den2+den3);
    float4 acc;
    acc.x = (acc0.x+acc1.x) + (acc2.x+acc3.x);
    acc.y = (acc0.y+acc1.y) + (acc2.y+acc3.y);
    acc.z = (acc0.z+acc1.z) + (acc2.z+acc3.z);
    acc.w = (acc0.w+acc1.w) + (acc2.w+acc3.w);
    float inv = 1.f / fmaxf(denom, 1e-9f);
    float4 b4 = *(const float4*)&bias[lane*4];
    s_out[wv][lane*4+0] = acc.x*inv + b4.x;
    s_out[wv][lane*4+1] = acc.y*inv + b4.y;
    s_out[wv][lane*4+2] = acc.z*inv + b4.z;
    s_out[wv][lane*4+3] = acc.w*inv + b4.w;
  }
  __syncthreads();
  if(valid && lane < 40){
    logits[(size_t)n*40 + lane] =
        0.25f * (s_out[wv][lane] + s_out[wv][40+lane] + s_out[wv][80+lane] + s_out[wv][120+lane]);
  }
}

extern "C" void kernel_launch(void* const* d_in, const int* in_sizes, int n_in,
                              void* d_out, int out_size, void* d_ws, size_t ws_size,
                              hipStream_t stream){
  const float* x   = (const float*)d_in[0];
  const int*   eix = (const int*)  d_in[1];
  const float* W0  = (const float*)d_in[2];
  const float* al0 = (const float*)d_in[3];
  const float* ar0 = (const float*)d_in[4];
  const float* b0  = (const float*)d_in[5];
  const float* W1  = (const float*)d_in[6];
  const float* al1 = (const float*)d_in[7];
  const float* ar1 = (const float*)d_in[8];
  const float* b1  = (const float*)d_in[9];
  const float* W2  = (const float*)d_in[10];
  const float* al2 = (const float*)d_in[11];
  const float* ar2 = (const float*)d_in[12];
  const float* b2  = (const float*)d_in[13];
  float* logits = (float*)d_out;

  const int N = in_sizes[0] / 256;   // 50000
  const int E = in_sizes[1] / 2;     // 800000
  const int* src = eix;
  const int* dst = eix + E;
  const int nb = (N + 1023) / 1024;

  char* ws = (char*)d_ws;
  auto alloc = [&](size_t bytes)->char*{
    char* p = ws; ws += (bytes + 255) & ~(size_t)255; return p;
  };
  int*   counts    = (int*)  alloc((size_t)N*4);
  int*   offsets   = (int*)  alloc((size_t)(N+1)*4);
  int*   cursor    = (int*)  alloc((size_t)N*4);
  int*   blocksums = (int*)  alloc((size_t)nb*4);
  int*   ssrc      = (int*)  alloc((size_t)E*4);
  int*   sdst      = (int*)  alloc((size_t)E*4);
  float* ew        = (float*)alloc((size_t)E*4*4);
  __hip_bfloat16* bufF = (__hip_bfloat16*)alloc((size_t)N*256*2);   // bf16 feat
  float* bufH      = (float*)alloc((size_t)N*256*4);                 // fp32 layer output
  float* el_buf    = (float*)alloc((size_t)N*4*4);
  float* er_buf    = (float*)alloc((size_t)N*4*4);
  ushortT* Wth0 = (ushortT*)alloc(256*256*2);
  ushortT* Wtl0 = (ushortT*)alloc(256*256*2);
  ushortT* Wth1 = (ushortT*)alloc(256*256*2);
  ushortT* Wtl1 = (ushortT*)alloc(256*256*2);
  ushortT* Wth2 = (ushortT*)alloc(256*256*2);
  ushortT* Wtl2 = (ushortT*)alloc(256*256*2);

  // sort edges by dst (graph fixed across layers — one sort per call)
  hipMemsetAsync(counts, 0, (size_t)N*4, stream);
  hist_kernel   <<<(E+255)/256, 256, 0, stream>>>(dst, E, counts);
  scan1_kernel  <<<nb, 1024, 0, stream>>>(counts, N, offsets, blocksums);
  scan2_kernel  <<<1, 64, 0, stream>>>(blocksums, nb);
  scan3_kernel  <<<nb, 1024, 0, stream>>>(offsets, blocksums, N, E, cursor);
  scatter_kernel<<<(E+255)/256, 256, 0, stream>>>(src, dst, E, cursor, ssrc, sdst);

  // W pre-transpose + bf16 hi/lo split (tiny)
  wsplit_kernel<<<256, 256, 0, stream>>>(W0, 256, Wth0, Wtl0);
  wsplit_kernel<<<256, 256, 0, stream>>>(W1, 256, Wth1, Wtl1);
  wsplit_kernel<<<256, 256, 0, stream>>>(W2, 160, Wth2, Wtl2);

  dim3 gg(2, (N + GBM - 1)/GBM);   // N cols 256 (or 160 padded to 256) -> 2 col-tiles
  int aggGrid = (N+3)/4;
  int ewGrid  = (E+255)/256;
  // layer 0
  gemm_mfma<<<gg, 256, 0, stream>>>(x, Wth0, Wtl0, (ushortT*)bufF, N, 256, 256);
  attn_proj_bf<<<N, 256, 0, stream>>>(bufF, al0, ar0, el_buf, er_buf, 64);
  edge_w_kernel<<<ewGrid, 256, 0, stream>>>(ssrc, sdst, E, (const float4*)el_buf, (const float4*)er_buf, (float4*)ew);
  agg_kernel<<<aggGrid, 256, 0, stream>>>((const uint2*)bufF, ew, offsets, ssrc, b0, bufH, N);
  // layer 1
  gemm_mfma<<<gg, 256, 0, stream>>>(bufH, Wth1, Wtl1, (ushortT*)bufF, N, 256, 256);
  attn_proj_bf<<<N, 256, 0, stream>>>(bufF, al1, ar1, el_buf, er_buf, 64);
  edge_w_kernel<<<ewGrid, 256, 0, stream>>>(ssrc, sdst, E, (const float4*)el_buf, (const float4*)er_buf, (float4*)ew);
  agg_kernel<<<aggGrid, 256, 0, stream>>>((const uint2*)bufF, ew, offsets, ssrc, b1, bufH, N);
  // layer 2 (N=160; Wt padded to 256 rows of zeros, stores guarded)
  gemm_mfma<<<gg, 256, 0, stream>>>(bufH, Wth2, Wtl2, (ushortT*)bufF, N, 160, 256);
  attn_proj_bf<<<N, 256, 0, stream>>>(bufF, al2, ar2, el_buf, er_buf, 40);
  edge_w_kernel<<<ewGrid, 256, 0, stream>>>(ssrc, sdst, E, (const float4*)el_buf, (const float4*)er_buf, (float4*)ew);
  agg2_kernel<<<aggGrid, 256, 0, stream>>>((const uint2*)bufF, ew, offsets, ssrc, b2, logits, N);
}